// Round 1
// 891.386 us; speedup vs baseline: 1.3793x; 1.3793x over previous
//
#include <hip/hip_runtime.h>
#include <hip/hip_bf16.h>

#define HID 256
#define NH 4
#define DH 64

typedef __attribute__((ext_vector_type(8))) short bf16x8;
typedef __attribute__((ext_vector_type(4))) float f32x4;

#define MFMA16(a, b, c) __builtin_amdgcn_mfma_f32_16x16x32_bf16((a), (b), (c), 0, 0, 0)

// LDS row strides (bf16 elems); all give 16B-aligned rows, stride%32dw==4 (2-way max aliasing)
#define LQK 72
#define LVT 136
#define LPB 136

__device__ __forceinline__ short f2bf(float f) {       // RNE fp32->bf16 (finite inputs)
  unsigned u = __float_as_uint(f);
  unsigned r = (u + 0x7fffu + ((u >> 16) & 1u)) >> 16;
  return (short)r;
}

__device__ __forceinline__ bf16x8 ld_cvt8(const float* p) {  // 8 fp32 -> bf16x8
  float4 a = *(const float4*)p;
  float4 b = *(const float4*)(p + 4);
  bf16x8 r;
  r[0] = f2bf(a.x); r[1] = f2bf(a.y); r[2] = f2bf(a.z); r[3] = f2bf(a.w);
  r[4] = f2bf(b.x); r[5] = f2bf(b.y); r[6] = f2bf(b.z); r[7] = f2bf(b.w);
  return r;
}

// One-shot weight conversion: Wq,Wk,Wv,Wo fp32 -> bf16 into ws (4 x 256x256 = 512KB).
// Removes the per-block x per-wave f2bf of weights that dominated VALU in both kernels.
__global__ __launch_bounds__(256) void cvt_w_kernel(
    const float* __restrict__ Wq, const float* __restrict__ Wk,
    const float* __restrict__ Wv, const float* __restrict__ Wo,
    short* __restrict__ Wb)
{
  const int i = (blockIdx.x * 256 + threadIdx.x) * 4;   // 64 blocks cover 65536 elems
  const float* src[4] = {Wq, Wk, Wv, Wo};
  #pragma unroll
  for (int m = 0; m < 4; m++) {
    float4 v = *(const float4*)(src[m] + i);
    short4 r;
    r.x = f2bf(v.x); r.y = f2bf(v.y); r.z = f2bf(v.z); r.w = f2bf(v.w);
    *(short4*)(Wb + m * (HID * HID) + i) = r;
  }
}

// One block per (molecule, head); 4 waves. MFMA QKV + flash-style attention.
// A-frag: A[m=lane&15][k=(lane>>4)*8+j]; B-frag: B^T rows, n=lane&15, same k pattern.
// C/D:    D[row=(lane>>4)*4+reg][col=lane&15]   (m89/m91-verified layouts)
__global__ __launch_bounds__(256) void attn_kernel(
    const float* __restrict__ msg, const short* __restrict__ Wb,
    const int* __restrict__ starts, const int* __restrict__ sizes,
    short* __restrict__ O)
{
  __shared__ __align__(16) short K_s[128 * LQK];      // K rows (B-operand for QK^T)
  __shared__ __align__(16) short V_t[DH * LVT];       // V transposed (B-operand for PV)
  __shared__ __align__(16) short P_s[4 * 16 * LPB];   // per-wave Q-scratch / P transpose

  const int mol  = blockIdx.x >> 2;
  const int head = blockIdx.x & 3;
  const int L     = sizes[mol];
  const int start = starts[mol];
  const int Mt  = (L + 15) >> 4;        // 16-row q tiles (2..8)
  const int NtE = Mt + (Mt & 1);        // key-tile count rounded even (PV k-step = 32)

  const int tid  = threadIdx.x;
  const int wave = tid >> 6;
  const int lane = tid & 63;
  const int c = lane & 15;              // "n"/"m" index within tile
  const int g = lane >> 4;              // k-quad / row-quad
  short* Pw = P_s + wave * (16 * LPB);

  // zero V_t pad columns [Mt*16, Mt*16+16) when Mt odd (PV reads NtE*16 cols)
  if (Mt & 1) {
    unsigned* vz = (unsigned*)V_t;
    for (int f = tid; f < DH * 8; f += 256)
      vz[(f >> 3) * (LVT / 2) + Mt * 8 + (f & 7)] = 0u;
  }

  const int mt0 = wave, mt1 = wave + 4;
  const bool h0 = mt0 < Mt, h1 = mt1 < Mt;
  bf16x8 qf[2][2];                       // Q A-frags (K=64 -> 2 k-steps) per owned m-tile

  // ================= Phase 1: QKV projection (MFMA) =================
  if (h0) {
    bf16x8 a0[8], a1[8];                 // X A-frags, 8 k-steps of K=256
    const bf16x8 zf = {0, 0, 0, 0, 0, 0, 0, 0};
    {
      int rl = mt0 * 16 + c;
      bool v = rl < L;
      const float* xp = msg + (size_t)(start + (v ? rl : 0)) * HID + g * 8;
      #pragma unroll
      for (int ks = 0; ks < 8; ks++) { bf16x8 t = ld_cvt8(xp + ks * 32); a0[ks] = v ? t : zf; }
    }
    if (h1) {
      int rl = mt1 * 16 + c;
      bool v = rl < L;
      const float* xp = msg + (size_t)(start + (v ? rl : 0)) * HID + g * 8;
      #pragma unroll
      for (int ks = 0; ks < 8; ks++) { bf16x8 t = ld_cvt8(xp + ks * 32); a1[ks] = v ? t : zf; }
    }

    const short* Wsec[3] = {Wb, Wb + HID * HID, Wb + 2 * HID * HID};
    #pragma unroll
    for (int nt = 0; nt < 12; nt++) {    // 192 output cols: q(0-3) k(4-7) v(8-11)
      const short* Wp = Wsec[nt >> 2] + (size_t)(head * 64 + (nt & 3) * 16 + c) * HID + g * 8;
      bf16x8 b[8];
      #pragma unroll
      for (int ks = 0; ks < 8; ks++) b[ks] = *(const bf16x8*)(Wp + ks * 32);

      #pragma unroll
      for (int i = 0; i < 2; i++) {
        if (i == 1 && !h1) continue;
        f32x4 acc = {0.f, 0.f, 0.f, 0.f};
        #pragma unroll
        for (int ks = 0; ks < 8; ks++)
          acc = MFMA16((i == 0 ? a0[ks] : a1[ks]), b[ks], acc);
        const int mt = (i == 0) ? mt0 : mt1;
        #pragma unroll
        for (int r = 0; r < 4; r++) {
          short val = f2bf(acc[r]);
          int row = mt * 16 + g * 4 + r;                    // < Mt*16 always
          if (nt < 4)       Pw[(g * 4 + r) * LPB + i * 64 + nt * 16 + c] = val;   // Q scratch
          else if (nt < 8)  K_s[row * LQK + (nt - 4) * 16 + c] = val;             // K row-major
          else              V_t[((nt - 8) * 16 + c) * LVT + row] = val;           // V transposed
        }
      }
      if (nt == 3) {                      // Q written -> pull A-operand frags
        __threadfence_block();
        #pragma unroll
        for (int i = 0; i < 2; i++)
          #pragma unroll
          for (int ks = 0; ks < 2; ks++)
            qf[i][ks] = *(const bf16x8*)&Pw[c * LPB + i * 64 + ks * 32 + g * 8];
      }
    }
  }
  __syncthreads();   // uniform: all K_s / V_t visible

  // ================= Phase 2: attention per owned q-tile =================
  const float scale = 0.125f;  // DH^-0.5
  #pragma unroll
  for (int i = 0; i < 2; i++) {
    int mt = wave + 4 * i;
    if (mt >= Mt) continue;

    // ---- S = Q K^T (C-layout in regs) ----
    float sv[8][4];
    #pragma unroll
    for (int nt = 0; nt < 8; nt++) {
      if (nt < NtE) {
        f32x4 acc = {0.f, 0.f, 0.f, 0.f};
        #pragma unroll
        for (int ks = 0; ks < 2; ks++) {
          bf16x8 kb = *(const bf16x8*)&K_s[(nt * 16 + c) * LQK + ks * 32 + g * 8];
          acc = MFMA16(qf[i][ks], kb, acc);
        }
        sv[nt][0] = acc[0]; sv[nt][1] = acc[1]; sv[nt][2] = acc[2]; sv[nt][3] = acc[3];
      }
    }

    // ---- softmax per row (row = g*4+r lives in lanes [g*16, g*16+16)) ----
    #pragma unroll
    for (int r = 0; r < 4; r++) {
      float mr = -3.0e38f;
      #pragma unroll
      for (int nt = 0; nt < 8; nt++) {
        if (nt < NtE) {
          bool valid = (nt * 16 + c) < L;
          float v = valid ? sv[nt][r] * scale : -3.0e38f;
          sv[nt][r] = v;
          mr = fmaxf(mr, v);
        }
      }
      mr = fmaxf(mr, __shfl_xor(mr, 1));
      mr = fmaxf(mr, __shfl_xor(mr, 2));
      mr = fmaxf(mr, __shfl_xor(mr, 4));
      mr = fmaxf(mr, __shfl_xor(mr, 8));
      float sum = 0.f;
      #pragma unroll
      for (int nt = 0; nt < 8; nt++) {
        if (nt < NtE) {
          float e = (sv[nt][r] > -1.0e37f) ? __expf(sv[nt][r] - mr) : 0.f;
          sv[nt][r] = e;
          sum += e;
        }
      }
      sum += __shfl_xor(sum, 1);
      sum += __shfl_xor(sum, 2);
      sum += __shfl_xor(sum, 4);
      sum += __shfl_xor(sum, 8);
      float inv = 1.f / sum;
      #pragma unroll
      for (int nt = 0; nt < 8; nt++)
        if (nt < NtE)
          Pw[(g * 4 + r) * LPB + nt * 16 + c] = f2bf(sv[nt][r] * inv);
    }
    __threadfence_block();   // P transpose round-trip, same wave

    // ---- O = P V, ReLU, store bf16 to ws ----
    #pragma unroll
    for (int nt2 = 0; nt2 < 4; nt2++) {
      f32x4 acc = {0.f, 0.f, 0.f, 0.f};
      #pragma unroll
      for (int ks = 0; ks < 4; ks++) {
        if (ks * 2 < NtE) {
          bf16x8 pa = *(const bf16x8*)&Pw[c * LPB + ks * 32 + g * 8];
          bf16x8 vb = *(const bf16x8*)&V_t[(nt2 * 16 + c) * LVT + ks * 32 + g * 8];
          acc = MFMA16(pa, vb, acc);
        }
      }
      #pragma unroll
      for (int r = 0; r < 4; r++) {
        int rl = mt * 16 + g * 4 + r;
        if (rl < L)
          O[(size_t)(start + rl) * HID + head * 64 + nt2 * 16 + c] =
              f2bf(fmaxf(acc[r], 0.f));
      }
    }
  }
}

// MFMA out-projection + bias + LayerNorm. Block = 32 rows, wave owns 64 cols.
__global__ __launch_bounds__(256) void proj_ln_kernel(
    const short* __restrict__ Ob, const short* __restrict__ Wob,
    const float* __restrict__ bo, const float* __restrict__ gamma,
    const float* __restrict__ beta, float* __restrict__ out, int total)
{
  __shared__ __align__(16) float o_s[32 * 260];   // 33.3 KB, stride 260 (1040B, 16B-aligned)
  const int base = blockIdx.x * 32;
  const int tid  = threadIdx.x;
  const int wave = tid >> 6;
  const int lane = tid & 63;
  const int c = lane & 15, g = lane >> 4;

  // A-frags from O (already bf16)
  bf16x8 a[2][8];
  #pragma unroll
  for (int i = 0; i < 2; i++) {
    int row = base + i * 16 + c;
    if (row >= total) row = total - 1;
    const short* p = Ob + (size_t)row * HID + g * 8;
    #pragma unroll
    for (int ks = 0; ks < 8; ks++) a[i][ks] = *(const bf16x8*)(p + ks * 32);
  }

  #pragma unroll
  for (int nt = 0; nt < 4; nt++) {
    const short* Wp = Wob + (size_t)(wave * 64 + nt * 16 + c) * HID + g * 8;
    bf16x8 b[8];
    #pragma unroll
    for (int ks = 0; ks < 8; ks++) b[ks] = *(const bf16x8*)(Wp + ks * 32);
    #pragma unroll
    for (int i = 0; i < 2; i++) {
      f32x4 acc = {0.f, 0.f, 0.f, 0.f};
      #pragma unroll
      for (int ks = 0; ks < 8; ks++) acc = MFMA16(a[i][ks], b[ks], acc);
      #pragma unroll
      for (int r = 0; r < 4; r++)
        o_s[(i * 16 + g * 4 + r) * 260 + wave * 64 + nt * 16 + c] = acc[r];
    }
  }
  __syncthreads();

  // LayerNorm: wave handles 8 rows; lane covers 4 cols
  float4 bo4 = *(const float4*)(bo + lane * 4);
  float4 g4  = *(const float4*)(gamma + lane * 4);
  float4 b4  = *(const float4*)(beta + lane * 4);
  #pragma unroll
  for (int r8 = 0; r8 < 8; r8++) {
    int rl = wave * 8 + r8;
    float4 o = *(const float4*)&o_s[rl * 260 + lane * 4];
    o.x += bo4.x; o.y += bo4.y; o.z += bo4.z; o.w += bo4.w;
    float s  = o.x + o.y + o.z + o.w;
    float ss = o.x * o.x + o.y * o.y + o.z * o.z + o.w * o.w;
    #pragma unroll
    for (int off = 32; off; off >>= 1) { s += __shfl_xor(s, off); ss += __shfl_xor(ss, off); }
    float mu  = s * (1.f / HID);
    float var = ss * (1.f / HID) - mu * mu;
    float inv = rsqrtf(var + 1e-5f);
    int row = base + rl;
    if (row < total) {
      float4 res;
      res.x = (o.x - mu) * inv * g4.x + b4.x;
      res.y = (o.y - mu) * inv * g4.y + b4.y;
      res.z = (o.z - mu) * inv * g4.z + b4.z;
      res.w = (o.w - mu) * inv * g4.w + b4.w;
      if (row == 0) res = make_float4(0.f, 0.f, 0.f, 0.f);  // cached_zero_vector
      *(float4*)(out + (size_t)row * HID + lane * 4) = res;
    }
  }
}

extern "C" void kernel_launch(void* const* d_in, const int* in_sizes, int n_in,
                              void* d_out, int out_size, void* d_ws, size_t ws_size,
                              hipStream_t stream) {
  const float* msg   = (const float*)d_in[0];
  const float* Wq    = (const float*)d_in[1];
  const float* Wk    = (const float*)d_in[2];
  const float* Wv    = (const float*)d_in[3];
  const float* Wo    = (const float*)d_in[4];
  const float* bo    = (const float*)d_in[5];
  const float* gamma = (const float*)d_in[6];
  const float* beta  = (const float*)d_in[7];
  const int* starts  = (const int*)d_in[8];
  const int* sizes   = (const int*)d_in[9];

  const int nmols = in_sizes[8];
  const int total = in_sizes[0] / HID;

  short* O  = (short*)d_ws;                       // [total][HID] bf16 o_relu scratch (~84 MB, proven fits)
  short* Wb = O + (size_t)total * HID;            // 4 x 256x256 bf16 weights (+512 KB)

  cvt_w_kernel<<<(HID * HID) / (256 * 4), 256, 0, stream>>>(Wq, Wk, Wv, Wo, Wb);
  attn_kernel<<<nmols * NH, 256, 0, stream>>>(msg, Wb, starts, sizes, O);
  proj_ln_kernel<<<(total + 31) / 32, 256, 0, stream>>>(
      O, Wb + 3 * HID * HID, bo, gamma, beta, (float*)d_out, total);
}